// Round 6
// baseline (14.425 us; speedup 1.0000x reference)
//
#include <hip/hip_runtime.h>
#include <math.h>

#define PI_F 3.14159265358979323846f

typedef unsigned u32v2 __attribute__((ext_vector_type(2)));

__device__ __forceinline__ float2 cmul(float2 a, float2 b) {
    return make_float2(a.x * b.x - a.y * b.y, a.x * b.y + a.y * b.x);
}
__device__ __forceinline__ float2 cfma(float2 u, float2 v, float2 acc) {
    acc.x = fmaf(u.x, v.x, fmaf(-u.y, v.y, acc.x));
    acc.y = fmaf(u.x, v.y, fmaf(u.y, v.x, acc.y));
    return acc;
}

// ---- lane-exchange primitives, by pipe ----
__device__ __forceinline__ float dpp_x1(float x) {  // lane ^ 1 (quad_perm [1,0,3,2]) — VALU
    return __int_as_float(__builtin_amdgcn_update_dpp(0, __float_as_int(x), 0xB1, 0xF, 0xF, true));
}
__device__ __forceinline__ float dpp_x2(float x) {  // lane ^ 2 (quad_perm [2,3,0,1]) — VALU
    return __int_as_float(__builtin_amdgcn_update_dpp(0, __float_as_int(x), 0x4E, 0xF, 0xF, true));
}
__device__ __forceinline__ float dpp_x8(float x) {  // lane ^ 8 (row_ror:8; (i+8)&15 == i^8) — VALU
    return __int_as_float(__builtin_amdgcn_update_dpp(0, __float_as_int(x), 0x128, 0xF, 0xF, true));
}
__device__ __forceinline__ float swz_x4(float x) {  // lane ^ 4 (ds_swizzle BitMode xor=4) — DS
    return __int_as_float(__builtin_amdgcn_ds_swizzle(__float_as_int(x), 0x101F));
}
#if __has_builtin(__builtin_amdgcn_permlane32_swap)
__device__ __forceinline__ float pl32(float x, int l) {  // lane ^ 32 — VALU (HW-validated select)
    unsigned u = __float_as_uint(x);
    u32v2 r = __builtin_amdgcn_permlane32_swap(u, u, false, false);
    return __uint_as_float((l & 32) ? r.x : r.y);
}
#else
__device__ __forceinline__ float pl32(float x, int l) { return __shfl_xor(x, 32, 64); }
#endif
#if __has_builtin(__builtin_amdgcn_permlane16_swap)
__device__ __forceinline__ float pl16(float x, int l) {  // lane ^ 16 — VALU (same select pattern)
    unsigned u = __float_as_uint(x);
    u32v2 r = __builtin_amdgcn_permlane16_swap(u, u, false, false);
    return __uint_as_float((l & 16) ? r.x : r.y);
}
#else
__device__ __forceinline__ float pl16(float x, int l) { return __shfl_xor(x, 16, 64); }
#endif

// ---- gate application given partner fetch ----
__device__ __forceinline__ void gate_apply(float2 a[4], const float2 pa[4], float2 al, float2 be) {
    #pragma unroll
    for (int r = 0; r < 4; r++) a[r] = cfma(al, a[r], cmul(be, pa[r]));
}
__device__ __forceinline__ void gate_dpp1(float2 a[4], const float2* U, int l) {
    bool h = l & 1;
    float2 al = h ? U[3] : U[0], be = h ? U[2] : U[1];
    float2 pa[4];
    #pragma unroll
    for (int r = 0; r < 4; r++) { pa[r].x = dpp_x1(a[r].x); pa[r].y = dpp_x1(a[r].y); }
    gate_apply(a, pa, al, be);
}
__device__ __forceinline__ void gate_dpp2(float2 a[4], const float2* U, int l) {
    bool h = l & 2;
    float2 al = h ? U[3] : U[0], be = h ? U[2] : U[1];
    float2 pa[4];
    #pragma unroll
    for (int r = 0; r < 4; r++) { pa[r].x = dpp_x2(a[r].x); pa[r].y = dpp_x2(a[r].y); }
    gate_apply(a, pa, al, be);
}
__device__ __forceinline__ void gate_swz4(float2 a[4], const float2* U, int l) {
    bool h = l & 4;
    float2 al = h ? U[3] : U[0], be = h ? U[2] : U[1];
    float2 pa[4];
    #pragma unroll
    for (int r = 0; r < 4; r++) { pa[r].x = swz_x4(a[r].x); pa[r].y = swz_x4(a[r].y); }
    gate_apply(a, pa, al, be);
}
__device__ __forceinline__ void gate_dpp8(float2 a[4], const float2* U, int l) {
    bool h = l & 8;
    float2 al = h ? U[3] : U[0], be = h ? U[2] : U[1];
    float2 pa[4];
    #pragma unroll
    for (int r = 0; r < 4; r++) { pa[r].x = dpp_x8(a[r].x); pa[r].y = dpp_x8(a[r].y); }
    gate_apply(a, pa, al, be);
}
__device__ __forceinline__ void gate_pl16(float2 a[4], const float2* U, int l) {
    bool h = l & 16;
    float2 al = h ? U[3] : U[0], be = h ? U[2] : U[1];
    float2 pa[4];
    #pragma unroll
    for (int r = 0; r < 4; r++) { pa[r].x = pl16(a[r].x, l); pa[r].y = pl16(a[r].y, l); }
    gate_apply(a, pa, al, be);
}
__device__ __forceinline__ void gate_pl32(float2 a[4], const float2* U, int l) {
    bool h = l & 32;
    float2 al = h ? U[3] : U[0], be = h ? U[2] : U[1];
    float2 pa[4];
    #pragma unroll
    for (int r = 0; r < 4; r++) { pa[r].x = pl32(a[r].x, l); pa[r].y = pl32(a[r].y, l); }
    gate_apply(a, pa, al, be);
}
// 1q gate on local bit0 (qubit 9)
__device__ __forceinline__ void gate_b0(float2 a[4], const float2* U) {
    float2 u00 = U[0], u01 = U[1], u10 = U[2], u11 = U[3];
    float2 n0 = cfma(u00, a[0], cmul(u01, a[1]));
    float2 n1 = cfma(u10, a[0], cmul(u11, a[1]));
    float2 n2 = cfma(u00, a[2], cmul(u01, a[3]));
    float2 n3 = cfma(u10, a[2], cmul(u11, a[3]));
    a[0] = n0; a[1] = n1; a[2] = n2; a[3] = n3;
}
// 1q gate on local bit1 (qubit 8)
__device__ __forceinline__ void gate_b1(float2 a[4], const float2* U) {
    float2 u00 = U[0], u01 = U[1], u10 = U[2], u11 = U[3];
    float2 n0 = cfma(u00, a[0], cmul(u01, a[2]));
    float2 n2 = cfma(u10, a[0], cmul(u11, a[2]));
    float2 n1 = cfma(u00, a[1], cmul(u01, a[3]));
    float2 n3 = cfma(u10, a[1], cmul(u11, a[3]));
    a[0] = n0; a[1] = n1; a[2] = n2; a[3] = n3;
}

__global__ __launch_bounds__(256) void qsim_fused(const float* __restrict__ inputs,
                                                  const float* __restrict__ theta,
                                                  float* __restrict__ out) {
    const int b = blockIdx.x;
    const int T = threadIdx.x;
    const int l = T & 63;
    const int w = T >> 6;

    __shared__ float2 sm[40][4];
    __shared__ float2 ve[10][2];
    __shared__ float2 vq[10][2];
    __shared__ float2 m4s[4][16];
    __shared__ __align__(16) float2 xch[2][1024];
    __shared__ float red[4][10];

    // ---- stage A: 40 layer mats; 10 encoding vectors (double-angle recurrence) ----
    if (T < 40) {
        float a0 = tanhf(theta[T * 3 + 0]) * PI_F;
        float a1 = tanhf(theta[T * 3 + 1]) * PI_F;
        float a2 = tanhf(theta[T * 3 + 2]) * PI_F;
        float sz0, cz0; sincosf(a0 * 0.5f, &sz0, &cz0);
        float2 m00 = make_float2(cz0, -sz0);
        float2 m11 = make_float2(cz0,  sz0);
        float sy, cy; sincosf(a1 * 0.5f, &sy, &cy);
        float2 t00 = make_float2(cy * m00.x, cy * m00.y);
        float2 t01 = make_float2(-sy * m11.x, -sy * m11.y);
        float2 t10 = make_float2(sy * m00.x, sy * m00.y);
        float2 t11 = make_float2(cy * m11.x, cy * m11.y);
        float sz2, cz2; sincosf(a2 * 0.5f, &sz2, &cz2);
        float2 e0 = make_float2(cz2, -sz2), e1 = make_float2(cz2, sz2);
        t00 = cmul(e0, t00); t01 = cmul(e0, t01);
        t10 = cmul(e1, t10); t11 = cmul(e1, t11);
        float sx, cx; sincosf(a0 * 0.25f, &sx, &cx);
        sm[T][0] = make_float2(cx * t00.x + sx * t10.y, cx * t00.y - sx * t10.x);
        sm[T][1] = make_float2(cx * t01.x + sx * t11.y, cx * t01.y - sx * t11.x);
        sm[T][2] = make_float2(cx * t10.x + sx * t00.y, cx * t10.y - sx * t00.x);
        sm[T][3] = make_float2(cx * t11.x + sx * t01.y, cx * t11.y - sx * t01.x);
    } else if (T >= 64 && T < 74) {
        int q = T - 64;
        float x = tanhf(inputs[b * 10 + q]);
        float sA[6], cA[6];
        sincosf(0.25f * x, &sA[0], &cA[0]);
        #pragma unroll
        for (int j = 1; j < 6; j++) {
            sA[j] = 2.f * sA[j - 1] * cA[j - 1];
            cA[j] = 1.f - 2.f * sA[j - 1] * sA[j - 1];
        }
        float2 v0 = make_float2(1.f, 0.f), v1 = make_float2(0.f, 0.f);
        #pragma unroll
        for (int k = 0; k < 5; k++) {
            float sh = sA[k + 1], ch = cA[k + 1];   // RZ half-angle = x*2^(k-1)
            float2 n0 = cmul(make_float2(ch, -sh), v0);
            float2 n1 = cmul(make_float2(ch,  sh), v1);
            float sx = sA[k], cx = cA[k];            // RX half-angle = x*2^(k-2)
            v0 = make_float2(cx * n0.x + sx * n1.y, cx * n0.y - sx * n1.x);
            v1 = make_float2(cx * n1.x + sx * n0.y, cx * n1.y - sx * n0.x);
        }
        ve[q][0] = v0; ve[q][1] = v1;
    }
    __syncthreads();
    // ---- stage B: M4 for layers 1..3; vq = L0mat * ve ----
    if (T < 48) {
        int li = T >> 4, lyr = li + 1;
        int e = T & 15, row = e >> 2, col = e & 3;
        int sr = (row == 2) ? 3 : (row == 3) ? 2 : row;
        float sgn = (row == 2) ? -1.f : 1.f;
        float2 u0 = sm[lyr * 10 + 0][(sr >> 1) * 2 + (col >> 1)];
        float2 u1 = sm[lyr * 10 + 1][(sr & 1) * 2 + (col & 1)];
        float2 p = cmul(u0, u1);
        m4s[lyr][e] = make_float2(sgn * p.x, sgn * p.y);
    } else if (T >= 64 && T < 74) {
        int q = T - 64;
        float2 v0 = ve[q][0], v1 = ve[q][1];
        vq[q][0] = cfma(sm[q][0], v0, cmul(sm[q][1], v1));
        vq[q][1] = cfma(sm[q][2], v0, cmul(sm[q][3], v1));
    }
    __syncthreads();

    // ---- layer 0 closed form ----
    const int i0 = (w << 8) | (l << 2);
    float2 a[4];
    {
        int f1 = (i0 & 0x154) >> 1; int m = i0 ^ f1;
        int f2 = (m & 0x2AA) >> 1;  int sh = m ^ f2;
        float2 t76 = cmul(vq[7][(sh >> 2) & 1], vq[6][(sh >> 3) & 1]);
        float2 t54 = cmul(vq[5][(sh >> 4) & 1], vq[4][(sh >> 5) & 1]);
        float2 t32 = cmul(vq[3][(sh >> 6) & 1], vq[2][(sh >> 7) & 1]);
        float2 t10 = cmul(vq[1][(sh >> 8) & 1], vq[0][(sh >> 9) & 1]);
        float2 P = cmul(cmul(t76, t54), cmul(t32, t10));
        #pragma unroll
        for (int r = 0; r < 4; r++) {
            int i = i0 | r;
            int g1 = (i & 0x154) >> 1; int mm = i ^ g1;
            int g2 = (mm & 0x2AA) >> 1; int s = mm ^ g2;
            int neg = (__popc(g1 & ~i) + __popc(g2 & ~mm)) & 1;
            float2 t = cmul(vq[8][(s >> 1) & 1], vq[9][s & 1]);
            t = cmul(P, t);
            a[r] = neg ? make_float2(-t.x, -t.y) : t;
        }
    }

    // ---- composite CZ constants (CZ(0,1) excluded -> even mask 0xAA) ----
    int srcLane;
    float sg0, sg1, sg2, sg3;
    {
        #define CZP(r, SG) { int i = i0 | r; int g1 = (i & 0x154) >> 1; int mm = i ^ g1; \
                             int g2 = (mm & 0xAA) >> 1; int s = mm ^ g2; \
                             int neg = (__popc(g1 & ~i) + __popc(g2 & ~mm)) & 1; \
                             SG = neg ? -1.f : 1.f; if (r == 0) srcLane = (s >> 2) & 63; }
        CZP(0, sg0) CZP(1, sg1) CZP(2, sg2) CZP(3, sg3)
        #undef CZP
    }
    const bool Lb = l & 1;

    // ---- layers 1..3 ----
    #pragma unroll
    for (int L = 1; L < 4; L++) {
        const float2 (*G)[4] = (const float2(*)[4])&sm[L * 10 + 2];
        gate_pl32(a, G[0], l);        // qubit 2, lane bit 5 (VALU)
        gate_pl16(a, G[1], l);        // qubit 3, lane bit 4 (VALU)
        gate_dpp8(a, G[2], l);        // qubit 4, lane bit 3 (VALU, row_ror:8)
        gate_swz4(a, G[3], l);        // qubit 5, lane bit 2 (DS swizzle)
        gate_dpp2(a, G[4], l);        // qubit 6, lane bit 1 (VALU)
        gate_dpp1(a, G[5], l);        // qubit 7, lane bit 0 (VALU)
        gate_b1(a, G[6]);             // qubit 8 (local)
        gate_b0(a, G[7]);             // qubit 9 (local)
        // w-axis 4x4 (q0,q1 gates + even CZ(0,1))
        {
            int buf = L & 1;
            float4* wp = (float4*)&xch[buf][T << 2];
            wp[0] = make_float4(a[0].x, a[0].y, a[1].x, a[1].y);
            wp[1] = make_float4(a[2].x, a[2].y, a[3].x, a[3].y);
            __syncthreads();
            const float2* M4row = &m4s[L][w * 4];
            float2 mw = M4row[w];
            float2 n[4];
            #pragma unroll
            for (int r = 0; r < 4; r++) n[r] = cmul(mw, a[r]);
            #pragma unroll
            for (int j = 0; j < 3; j++) {
                int wo = (w + 1 + j) & 3;
                float2 c = M4row[wo];
                const float4* rp = (const float4*)&xch[buf][(wo << 8) | (l << 2)];
                float4 v0 = rp[0], v1 = rp[1];
                n[0] = cfma(c, make_float2(v0.x, v0.y), n[0]);
                n[1] = cfma(c, make_float2(v0.z, v0.w), n[1]);
                n[2] = cfma(c, make_float2(v1.x, v1.y), n[2]);
                n[3] = cfma(c, make_float2(v1.z, v1.w), n[3]);
            }
            a[0] = n[0]; a[1] = n[1]; a[2] = n[2]; a[3] = n[3];
        }
        // composite remaining CZs; last layer: signs irrelevant to |.|^2
        {
            float p0x = __shfl(a[0].x, srcLane, 64), p0y = __shfl(a[0].y, srcLane, 64);
            float p1x = __shfl(a[1].x, srcLane, 64), p1y = __shfl(a[1].y, srcLane, 64);
            float p2x = __shfl(a[2].x, srcLane, 64), p2y = __shfl(a[2].y, srcLane, 64);
            float p3x = __shfl(a[3].x, srcLane, 64), p3y = __shfl(a[3].y, srcLane, 64);
            if (L < 3) {
                a[0] = make_float2(sg0 * (Lb ? p3x : p0x), sg0 * (Lb ? p3y : p0y));
                a[1] = make_float2(sg1 * (Lb ? p2x : p1x), sg1 * (Lb ? p2y : p1y));
                a[2] = make_float2(sg2 * (Lb ? p0x : p3x), sg2 * (Lb ? p0y : p3y));
                a[3] = make_float2(sg3 * (Lb ? p1x : p2x), sg3 * (Lb ? p1y : p2y));
            } else {
                a[0] = make_float2(Lb ? p3x : p0x, Lb ? p3y : p0y);
                a[1] = make_float2(Lb ? p2x : p1x, Lb ? p2y : p1y);
                a[2] = make_float2(Lb ? p0x : p3x, Lb ? p0y : p3y);
                a[3] = make_float2(Lb ? p1x : p2x, Lb ? p1y : p2y);
            }
        }
    }

    // ---- expectations: one butterfly with per-bit signed captures ----
    float p0 = a[0].x * a[0].x + a[0].y * a[0].y;
    float p1 = a[1].x * a[1].x + a[1].y * a[1].y;
    float p2 = a[2].x * a[2].x + a[2].y * a[2].y;
    float p3 = a[3].x * a[3].x + a[3].y * a[3].y;
    float acc = p0 + p1 + p2 + p3;       // S
    float a8 = p0 + p1 - p2 - p3;        // qubit 8 (r bit1)
    float a9 = p0 - p1 + p2 - p3;        // qubit 9 (r bit0)
    float d0, d1, d2, d3, d4, d5;
    // stage 1 (DPP)
    { float pS = dpp_x1(acc); d0 = (l & 1) ? pS - acc : acc - pS; acc += pS;
      a8 += dpp_x1(a8); a9 += dpp_x1(a9); }
    // stage 2 (DPP)
    { float pS = dpp_x2(acc); d1 = (l & 2) ? pS - acc : acc - pS; acc += pS;
      a8 += dpp_x2(a8); a9 += dpp_x2(a9); d0 += dpp_x2(d0); }
    // stage 4 (DS swizzle)
    { float pS = swz_x4(acc); d2 = (l & 4) ? pS - acc : acc - pS; acc += pS;
      a8 += swz_x4(a8); a9 += swz_x4(a9);
      d0 += swz_x4(d0); d1 += swz_x4(d1); }
    // stage 8 (DPP row_ror:8)
    { float pS = dpp_x8(acc); d3 = (l & 8) ? pS - acc : acc - pS; acc += pS;
      a8 += dpp_x8(a8); a9 += dpp_x8(a9);
      d0 += dpp_x8(d0); d1 += dpp_x8(d1); d2 += dpp_x8(d2); }
    // stage 16 (permlane16, VALU)
    { float pS = pl16(acc, l); d4 = (l & 16) ? pS - acc : acc - pS; acc += pS;
      a8 += pl16(a8, l); a9 += pl16(a9, l);
      d0 += pl16(d0, l); d1 += pl16(d1, l);
      d2 += pl16(d2, l); d3 += pl16(d3, l); }
    // stage 32 (permlane32, VALU)
    { float pS = pl32(acc, l); d5 = (l & 32) ? pS - acc : acc - pS; acc += pS;
      a8 += pl32(a8, l); a9 += pl32(a9, l);
      d0 += pl32(d0, l); d1 += pl32(d1, l); d2 += pl32(d2, l);
      d3 += pl32(d3, l); d4 += pl32(d4, l); }

    if (l == 0) {
        red[w][0] = (w & 2) ? -acc : acc;   // qubit 0 (w bit1)
        red[w][1] = (w & 1) ? -acc : acc;   // qubit 1 (w bit0)
        red[w][2] = d5;  // qubit 2 <- lane bit 5
        red[w][3] = d4;
        red[w][4] = d3;
        red[w][5] = d2;
        red[w][6] = d1;
        red[w][7] = d0;  // qubit 7 <- lane bit 0
        red[w][8] = a8;
        red[w][9] = a9;
    }
    __syncthreads();
    if (T < 10) {
        out[b * 10 + T] = red[0][T] + red[1][T] + red[2][T] + red[3][T];
    }
}

extern "C" void kernel_launch(void* const* d_in, const int* in_sizes, int n_in,
                              void* d_out, int out_size, void* d_ws, size_t ws_size,
                              hipStream_t stream) {
    const float* inputs = (const float*)d_in[0];  // (512, 10) f32
    const float* theta  = (const float*)d_in[1];  // (4, 10, 3) f32
    float* out = (float*)d_out;                    // (512, 10) f32
    qsim_fused<<<512, 256, 0, stream>>>(inputs, theta, out);
}